// Round 5
// baseline (361.670 us; speedup 1.0000x reference)
//
#include <hip/hip_runtime.h>

#define BB 32
#define NN 16384

typedef __attribute__((ext_vector_type(4))) float f4;
typedef __attribute__((ext_vector_type(8))) short short8;

__device__ __forceinline__ unsigned int f2bf(float f) {
  unsigned int u = __float_as_uint(f);
  return (u + 0x7fffu + ((u >> 16) & 1u)) >> 16;
}
__device__ __forceinline__ short bfs(float f) { return (short)f2bf(f); }
__device__ __forceinline__ float bf2f(unsigned short h) {
  return __uint_as_float(((unsigned int)h) << 16);
}

// ---------------------------------------------------------------------------
// prep: Wk, Wv fp32 -> bf16
// ---------------------------------------------------------------------------
__global__ void __launch_bounds__(256) prep_kernel(
    const float* __restrict__ Wk, const float* __restrict__ Wv,
    unsigned short* __restrict__ Wkb, unsigned short* __restrict__ Wvb)
{
  int id = blockIdx.x * 256 + threadIdx.x;  // grid 16 -> 4096
  Wkb[id] = (unsigned short)f2bf(Wk[id]);
  Wvb[id] = (unsigned short)f2bf(Wv[id]);
}

// ---------------------------------------------------------------------------
// init_q: slots = mu + exp(lsig)*noise; q = bf16(LN(slots)@Wq^T * 0.125).
// ---------------------------------------------------------------------------
__global__ void __launch_bounds__(64) init_q_kernel(
    const float* __restrict__ noise, const float* __restrict__ mu,
    const float* __restrict__ lsig, float* __restrict__ slots,
    const float* __restrict__ gs, const float* __restrict__ bsl,
    const float* __restrict__ Wq, unsigned short* __restrict__ qb)
{
  const int bsi = blockIdx.x, l = threadIdx.x;
  const int idx = bsi * 64 + l;
  __shared__ float sh[64];
  float v = mu[idx & 511] + __expf(lsig[idx & 511]) * noise[idx];
  slots[idx] = v;
  float sm = v, sq = v * v;
#pragma unroll
  for (int m = 1; m < 64; m <<= 1) { sm += __shfl_xor(sm, m); sq += __shfl_xor(sq, m); }
  float mean = sm * (1.f / 64.f);
  float var = sq * (1.f / 64.f) - mean * mean;
  sh[l] = (v - mean) * rsqrtf(var + 1e-5f) * gs[l] + bsl[l];
  float acc = 0.f;
  const float* w = Wq + l * 64;
  for (int k = 0; k < 64; ++k) acc += sh[k] * w[k];
  qb[idx] = (unsigned short)f2bf(acc * 0.125f);
}

// ---------------------------------------------------------------------------
// proj v3: dt-outer, W register-resident across 4 groups; all-group LN first.
// Layouts (shorts):
//   Ktb (B-frag d-major): (b<<20) + (nblk<<10) + (h<<9) + ((n&15)<<5)
//                         + (quadB<<3) + j,  d = h*32 + quadB*8 + j
//   Vtf (d-major):        (b<<20) + (nblk<<10) + (d<<4) + (n&15)
// 2048 blocks x 256 rows (4 waves x 16-row strips x 4 groups).
// ---------------------------------------------------------------------------
__global__ void __launch_bounds__(256) proj_kernel(
    const float* __restrict__ x, const float* __restrict__ gin, const float* __restrict__ bin,
    const unsigned short* __restrict__ Wkb, const unsigned short* __restrict__ Wvb,
    unsigned short* __restrict__ Ktb, unsigned short* __restrict__ Vtf)
{
  const int blk = blockIdx.x;
  const int tid = threadIdx.x, wave = tid >> 6, lane = tid & 63;
  const int l15 = lane & 15, quad = lane >> 4;
  const int b = blk >> 6;  // 64 blocks per batch
  const size_t row0 = ((size_t)blk << 8) + (wave << 4) + l15;
  const float* xp = x + row0 * 64 + quad * 8;
  const int k0 = quad * 8;

  f4 g0a = *(const f4*)(gin + k0),      g0b = *(const f4*)(gin + k0 + 4);
  f4 g1a = *(const f4*)(gin + k0 + 32), g1b = *(const f4*)(gin + k0 + 36);
  f4 h0a = *(const f4*)(bin + k0),      h0b = *(const f4*)(bin + k0 + 4);
  f4 h1a = *(const f4*)(bin + k0 + 32), h1b = *(const f4*)(bin + k0 + 36);

  // Phase 1: LN of all 4 groups (independent chains, loads batched in flight)
  short8 a0[4], a1[4];
#pragma unroll
  for (int g = 0; g < 4; ++g) {
    const float* p = xp + (size_t)g * 4096;
    f4 c0 = *(const f4*)p,        c1 = *(const f4*)(p + 4);
    f4 c2 = *(const f4*)(p + 32), c3 = *(const f4*)(p + 36);
    float sm = 0.f, sq = 0.f;
#pragma unroll
    for (int j = 0; j < 4; ++j) {
      sm += c0[j] + c1[j] + c2[j] + c3[j];
      sq += c0[j]*c0[j] + c1[j]*c1[j] + c2[j]*c2[j] + c3[j]*c3[j];
    }
    sm += __shfl_xor(sm, 16); sq += __shfl_xor(sq, 16);
    sm += __shfl_xor(sm, 32); sq += __shfl_xor(sq, 32);
    const float mean = sm * (1.f / 64.f);
    const float var = sq * (1.f / 64.f) - mean * mean;
    const float rstd = rsqrtf(var + 1e-5f);
#pragma unroll
    for (int j = 0; j < 4; ++j) {
      a0[g][j]     = bfs((c0[j] - mean) * rstd * g0a[j] + h0a[j]);
      a0[g][j + 4] = bfs((c1[j] - mean) * rstd * g0b[j] + h0b[j]);
      a1[g][j]     = bfs((c2[j] - mean) * rstd * g1a[j] + h1a[j]);
      a1[g][j + 4] = bfs((c3[j] - mean) * rstd * g1b[j] + h1b[j]);
    }
  }

  // Phase 2: dt-outer (W loaded once per dt), 4 groups inner
  const int nblk0 = ((blk & 63) << 4) + wave;  // + g*4
  unsigned short* Kbase = Ktb + ((size_t)b << 20);
  unsigned short* Vbase = Vtf + ((size_t)b << 20);

#pragma unroll
  for (int dt = 0; dt < 4; ++dt) {
    const unsigned short* wkp = Wkb + ((dt << 4) + l15) * 64 + k0;
    const unsigned short* wvp = Wvb + ((dt << 4) + l15) * 64 + k0;
    short8 wk0 = *(const short8*)wkp, wk1 = *(const short8*)(wkp + 32);
    short8 wv0 = *(const short8*)wvp, wv1 = *(const short8*)(wvp + 32);
    // K C-layout: lane holds K[n=l15][d = dt*16 + quad*4 + reg]
    //   -> Ktb: h=dt>>1, quadB=(dt&1)*2+(quad>>1), j=(quad&1)*4+reg (uint2)
    const int koff = ((dt >> 1) << 9) + (l15 << 5) +
                     ((((dt & 1) << 1) | (quad >> 1)) << 3) + ((quad & 1) << 2);
    // V C-layout: lane holds V[n = quad*4+reg][d = dt*16 + l15] (uint2 along n)
    const int voff = (((dt << 4) + l15) << 4) + (quad << 2);
#pragma unroll
    for (int g = 0; g < 4; ++g) {
      f4 ak = {0.f, 0.f, 0.f, 0.f}, av = {0.f, 0.f, 0.f, 0.f};
      ak = __builtin_amdgcn_mfma_f32_16x16x32_bf16(wk0, a0[g], ak, 0, 0, 0);
      ak = __builtin_amdgcn_mfma_f32_16x16x32_bf16(wk1, a1[g], ak, 0, 0, 0);
      av = __builtin_amdgcn_mfma_f32_16x16x32_bf16(a0[g], wv0, av, 0, 0, 0);
      av = __builtin_amdgcn_mfma_f32_16x16x32_bf16(a1[g], wv1, av, 0, 0, 0);
      const size_t nb10 = (size_t)(nblk0 + (g << 2)) << 10;
      uint2 kk, vv;
      kk.x = f2bf(ak[0]) | (f2bf(ak[1]) << 16);
      kk.y = f2bf(ak[2]) | (f2bf(ak[3]) << 16);
      vv.x = f2bf(av[0]) | (f2bf(av[1]) << 16);
      vv.y = f2bf(av[2]) | (f2bf(av[3]) << 16);
      *(uint2*)(Kbase + nb10 + koff) = kk;
      *(uint2*)(Vbase + nb10 + voff) = vv;
    }
  }
}

// ---------------------------------------------------------------------------
// reduce v3: s-major logits. lg = mfma(qA, kB): C[row=s_slot][col=n] -> lane
// holds 4 s of one n; softmax = 3 in-lane adds + ONE xor16 shuffle + rcp.
// P transposed to A-layout via per-wave LDS (4 b16 writes/lane); csum from
// in-register unpack of the P A-frag (bitwise-consistent with Wpart).
// grid 2048 = 32 b x 64 ch(256 rows), block 256 = 4 waves x 64 rows.
// ---------------------------------------------------------------------------
__global__ void __launch_bounds__(256) reduce_kernel(
    const unsigned short* __restrict__ Ktb, const unsigned short* __restrict__ Vtf,
    const unsigned short* __restrict__ qb,
    float* __restrict__ Wpart, float* __restrict__ cpart)
{
  __shared__ __align__(16) unsigned short Pt[4][16][40];
  __shared__ float red[4][512];
  __shared__ float cred[4][8];

  const int tid = threadIdx.x, wave = tid >> 6, lane = tid & 63;
  const int l15 = lane & 15, quad = lane >> 4;
  const int b = blockIdx.x >> 6, ch = blockIdx.x & 63;

  // q A-frag: row m = l15 (s = l15&7 dup), k = d = quad*8+j (+32 for h1)
  const unsigned short* qrow = qb + (((b << 3) + (l15 & 7)) << 6) + quad * 8;
  short8 qf0 = *(const short8*)qrow;
  short8 qf1 = *(const short8*)(qrow + 32);

  const unsigned short* Kb = Ktb + ((size_t)b << 20);
  const unsigned short* Vb = Vtf + ((size_t)b << 20);

  f4 wacc[4];
#pragma unroll
  for (int t = 0; t < 4; ++t) wacc[t] = (f4){0.f, 0.f, 0.f, 0.f};
  float cacc = 0.f;
  const int nb0 = (ch << 8) + (wave << 6);

#pragma unroll
  for (int u = 0; u < 2; ++u) {
    const int nblk0 = (nb0 + u * 32) >> 4;
    // K B-frags: dense 1KB/wave loads; ntile0 = nblk0, ntile1 = nblk0+1
    const unsigned short* kp = Kb + (nblk0 << 10) + (l15 << 5) + (quad << 3);
    short8 k00 = *(const short8*)kp;            // ntile0, d 0..31
    short8 k01 = *(const short8*)(kp + 512);    // ntile0, d 32..63
    short8 k10 = *(const short8*)(kp + 1024);   // ntile1, d 0..31
    short8 k11 = *(const short8*)(kp + 1536);
    short8 vf[4];
#pragma unroll
    for (int t = 0; t < 4; ++t)
      vf[t] = *(const short8*)(Vb + ((size_t)(nblk0 + (quad >> 1)) << 10) +
                               (((t << 4) + l15) << 4) + ((quad & 1) << 3));

#pragma unroll
    for (int nt = 0; nt < 2; ++nt) {
      f4 lg = {0.f, 0.f, 0.f, 0.f};
      lg = __builtin_amdgcn_mfma_f32_16x16x32_bf16(qf0, nt ? k10 : k00, lg, 0, 0, 0);
      lg = __builtin_amdgcn_mfma_f32_16x16x32_bf16(qf1, nt ? k11 : k01, lg, 0, 0, 0);
      // lane: lg[reg] = logit[s_slot = quad*4+reg][n-col = l15]
      float e0 = __expf(lg[0]), e1 = __expf(lg[1]);
      float e2 = __expf(lg[2]), e3 = __expf(lg[3]);
      float ss = (e0 + e1) + (e2 + e3);
      ss += __shfl_xor(ss, 16);  // quad 0<->1 (s 0..3 + 4..7), 2<->3 (dups)
      const float inv = __builtin_amdgcn_rcpf(ss);
      const int col = nt * 16 + l15;
      Pt[wave][quad * 4 + 0][col] = (unsigned short)f2bf(e0 * inv);
      Pt[wave][quad * 4 + 1][col] = (unsigned short)f2bf(e1 * inv);
      Pt[wave][quad * 4 + 2][col] = (unsigned short)f2bf(e2 * inv);
      Pt[wave][quad * 4 + 3][col] = (unsigned short)f2bf(e3 * inv);
    }
    // P A-frag: A[m=s=l15][k=n_local=quad*8+j] (same-wave DS order, no barrier)
    short8 pf = *(const short8*)&Pt[wave][l15][quad * 8];
#pragma unroll
    for (int i = 0; i < 8; ++i) cacc += bf2f((unsigned short)pf[i]);
#pragma unroll
    for (int t = 0; t < 4; ++t)
      wacc[t] = __builtin_amdgcn_mfma_f32_16x16x32_bf16(pf, vf[t], wacc[t], 0, 0, 0);
  }

  // cacc: lane holds sum over its 8 n per unit; xor16+xor32 -> all 32 n/unit
  cacc += __shfl_xor(cacc, 16);
  cacc += __shfl_xor(cacc, 32);
  if (lane < 8) cred[wave][lane] = cacc;
  if (quad < 2) {  // C rows 8..15 are s-duplicates
#pragma unroll
    for (int t = 0; t < 4; ++t)
#pragma unroll
      for (int r2 = 0; r2 < 4; ++r2)
        red[wave][(quad * 4 + r2) * 64 + (t << 4) + l15] = wacc[t][r2];
  }
  __syncthreads();
  for (int i = tid; i < 512; i += 256)
    Wpart[(size_t)blockIdx.x * 512 + i] = red[0][i] + red[1][i] + red[2][i] + red[3][i];
  if (tid < 8)
    cpart[blockIdx.x * 8 + tid] = cred[0][tid] + cred[1][tid] + cred[2][tid] + cred[3][tid];
}

// ---------------------------------------------------------------------------
// update: per (b,s), 256 threads. Chunk-reduce + GRU + LN + MLP + residual;
// emits next q when make_q.
// ---------------------------------------------------------------------------
__global__ void __launch_bounds__(256) update_kernel(
    const float* __restrict__ Wpart, const float* __restrict__ cpart,
    const float* __restrict__ slots, float* __restrict__ out,
    const float* __restrict__ W_ih, const float* __restrict__ W_hh,
    const float* __restrict__ b_ih, const float* __restrict__ b_hh,
    const float* __restrict__ g_mlp, const float* __restrict__ b_mlp,
    const float* __restrict__ W1, const float* __restrict__ b1,
    const float* __restrict__ W2, const float* __restrict__ b2,
    const float* __restrict__ gs, const float* __restrict__ bsl,
    const float* __restrict__ Wq, unsigned short* __restrict__ qb, int make_q)
{
  const int bs = blockIdx.x;
  const int b = bs >> 3, s = bs & 7;
  const int tid = threadIdx.x;
  const int l = tid & 63, cq = tid >> 6;
  __shared__ float wred[4][64];
  __shared__ float credS[4];
  __shared__ float u_sh[64], sp_sh[64], giA[192], ghA[192], uln_sh[64], h_sh[128];

  float wp = 0.f, cp2 = 0.f;
  for (int c = cq * 16; c < cq * 16 + 16; ++c) {
    wp += Wpart[(size_t)(((b << 6) + c) * 8 + s) * 64 + l];
    cp2 += cpart[((b << 6) + c) * 8 + s];
  }
  wred[cq][l] = wp;
  if (l == 0) credS[cq] = cp2;
  __syncthreads();

  float sp = 0.f;
  if (tid < 64) {
    const float cs = credS[0] + credS[1] + credS[2] + credS[3];
    const float u = (wred[0][l] + wred[1][l] + wred[2][l] + wred[3][l]) / cs;
    sp = slots[(b * 8 + s) * 64 + l];
    u_sh[l] = u; sp_sh[l] = sp;
  }
  __syncthreads();

  if (tid < 192) {
    float accI = b_ih[tid], accH = b_hh[tid];
    const float* wi = W_ih + tid * 64;
    const float* wh = W_hh + tid * 64;
    for (int k = 0; k < 64; ++k) { accI += u_sh[k] * wi[k]; accH += sp_sh[k] * wh[k]; }
    giA[tid] = accI; ghA[tid] = accH;
  }
  __syncthreads();

  float upd = 0.f;
  if (tid < 64) {
    const float rg = 1.f / (1.f + __expf(-(giA[l] + ghA[l])));
    const float zg = 1.f / (1.f + __expf(-(giA[64 + l] + ghA[64 + l])));
    const float ng = tanhf(giA[128 + l] + rg * ghA[128 + l]);
    upd = (1.f - zg) * ng + zg * sp;
    float sm = upd, sq = upd * upd;
#pragma unroll
    for (int m = 1; m < 64; m <<= 1) { sm += __shfl_xor(sm, m); sq += __shfl_xor(sq, m); }
    const float mean = sm * (1.f / 64.f);
    const float var = sq * (1.f / 64.f) - mean * mean;
    uln_sh[l] = (upd - mean) * rsqrtf(var + 1e-5f) * g_mlp[l] + b_mlp[l];
  }
  __syncthreads();

  if (tid < 128) {
    float acc = b1[tid];
    const float* w1 = W1 + tid * 64;
    for (int k = 0; k < 64; ++k) acc += uln_sh[k] * w1[k];
    h_sh[tid] = fmaxf(acc, 0.f);
  }
  __syncthreads();

  if (tid < 64) {
    float acc = b2[l];
    const float* w2 = W2 + l * 128;
    for (int k = 0; k < 128; ++k) acc += h_sh[k] * w2[k];
    const float sv = upd + acc;
    out[(b * 8 + s) * 64 + l] = sv;
    if (make_q) {
      float sm2 = sv, sq2 = sv * sv;
#pragma unroll
      for (int m = 1; m < 64; m <<= 1) { sm2 += __shfl_xor(sm2, m); sq2 += __shfl_xor(sq2, m); }
      const float mean2 = sm2 * (1.f / 64.f);
      const float var2 = sq2 * (1.f / 64.f) - mean2 * mean2;
      u_sh[l] = (sv - mean2) * rsqrtf(var2 + 1e-5f) * gs[l] + bsl[l];
      float qa = 0.f;
      const float* w = Wq + l * 64;
      for (int k = 0; k < 64; ++k) qa += u_sh[k] * w[k];
      qb[(b * 8 + s) * 64 + l] = (unsigned short)f2bf(qa * 0.125f);
    }
  }
}

// ---------------------------------------------------------------------------
extern "C" void kernel_launch(void* const* d_in, const int* in_sizes, int n_in,
                              void* d_out, int out_size, void* d_ws, size_t ws_size,
                              hipStream_t stream) {
  const float* x       = (const float*)d_in[0];
  const float* noise   = (const float*)d_in[1];
  const float* mu      = (const float*)d_in[2];
  const float* lsig    = (const float*)d_in[3];
  const float* ln_in_g = (const float*)d_in[4];
  const float* ln_in_b = (const float*)d_in[5];
  const float* ln_sl_g = (const float*)d_in[6];
  const float* ln_sl_b = (const float*)d_in[7];
  const float* ln_ml_g = (const float*)d_in[8];
  const float* ln_ml_b = (const float*)d_in[9];
  const float* Wq      = (const float*)d_in[10];
  const float* Wk      = (const float*)d_in[11];
  const float* Wv      = (const float*)d_in[12];
  const float* W_ih    = (const float*)d_in[13];
  const float* W_hh    = (const float*)d_in[14];
  const float* b_ih    = (const float*)d_in[15];
  const float* b_hh    = (const float*)d_in[16];
  const float* W1      = (const float*)d_in[17];
  const float* b1      = (const float*)d_in[18];
  const float* W2      = (const float*)d_in[19];
  const float* b2      = (const float*)d_in[20];

  unsigned short* Ktb = (unsigned short*)d_ws;
  unsigned short* Vt  = Ktb + (size_t)BB * NN * 64;
  unsigned short* Wkb = Vt + (size_t)BB * NN * 64;
  unsigned short* Wvb = Wkb + 4096;
  unsigned short* qb  = Wvb + 4096;
  float* slots = (float*)(qb + 16384);
  float* Wpart = slots + 32 * 8 * 64;
  float* cpart = Wpart + (size_t)2048 * 512;

  prep_kernel<<<dim3(16), dim3(256), 0, stream>>>(Wk, Wv, Wkb, Wvb);
  init_q_kernel<<<dim3(256), dim3(64), 0, stream>>>(
      noise, mu, lsig, slots, ln_sl_g, ln_sl_b, Wq, qb);
  proj_kernel<<<dim3(2048), dim3(256), 0, stream>>>(
      x, ln_in_g, ln_in_b, Wkb, Wvb, Ktb, Vt);

  for (int it = 0; it < 3; ++it) {
    reduce_kernel<<<dim3(2048), dim3(256), 0, stream>>>(Ktb, Vt, qb, Wpart, cpart);
    update_kernel<<<dim3(256), dim3(256), 0, stream>>>(
        Wpart, cpart, slots, (it == 2) ? (float*)d_out : slots,
        W_ih, W_hh, b_ih, b_hh, ln_ml_g, ln_ml_b, W1, b1, W2, b2,
        ln_sl_g, ln_sl_b, Wq, qb, (it < 2) ? 1 : 0);
  }
}

// Round 6
// 345.103 us; speedup vs baseline: 1.0480x; 1.0480x over previous
//
#include <hip/hip_runtime.h>

#define BB 32
#define NN 16384

typedef __attribute__((ext_vector_type(4))) float f4;
typedef __attribute__((ext_vector_type(8))) short short8;

__device__ __forceinline__ unsigned int f2bf(float f) {
  unsigned int u = __float_as_uint(f);
  return (u + 0x7fffu + ((u >> 16) & 1u)) >> 16;
}
__device__ __forceinline__ short bfs(float f) { return (short)f2bf(f); }

// ---------------------------------------------------------------------------
// prep: Wk, Wv fp32 -> bf16
// ---------------------------------------------------------------------------
__global__ void __launch_bounds__(256) prep_kernel(
    const float* __restrict__ Wk, const float* __restrict__ Wv,
    unsigned short* __restrict__ Wkb, unsigned short* __restrict__ Wvb)
{
  int id = blockIdx.x * 256 + threadIdx.x;  // grid 16 -> 4096
  Wkb[id] = (unsigned short)f2bf(Wk[id]);
  Wvb[id] = (unsigned short)f2bf(Wv[id]);
}

// ---------------------------------------------------------------------------
// init_q: slots = mu + exp(lsig)*noise; q = bf16(LN(slots)@Wq^T * 0.125).
// ---------------------------------------------------------------------------
__global__ void __launch_bounds__(64) init_q_kernel(
    const float* __restrict__ noise, const float* __restrict__ mu,
    const float* __restrict__ lsig, float* __restrict__ slots,
    const float* __restrict__ gs, const float* __restrict__ bsl,
    const float* __restrict__ Wq, unsigned short* __restrict__ qb)
{
  const int bsi = blockIdx.x, l = threadIdx.x;
  const int idx = bsi * 64 + l;
  __shared__ float sh[64];
  float v = mu[idx & 511] + __expf(lsig[idx & 511]) * noise[idx];
  slots[idx] = v;
  float sm = v, sq = v * v;
#pragma unroll
  for (int m = 1; m < 64; m <<= 1) { sm += __shfl_xor(sm, m); sq += __shfl_xor(sq, m); }
  float mean = sm * (1.f / 64.f);
  float var = sq * (1.f / 64.f) - mean * mean;
  sh[l] = (v - mean) * rsqrtf(var + 1e-5f) * gs[l] + bsl[l];
  float acc = 0.f;
  const float* w = Wq + l * 64;
  for (int k = 0; k < 64; ++k) acc += sh[k] * w[k];
  qb[idx] = (unsigned short)f2bf(acc * 0.125f);
}

// ---------------------------------------------------------------------------
// proj (R4 structure, 8 groups): Kf / Vtf fragment-packed layouts:
//   Kf  offset(shorts) = (b<<20) + (nblk<<10) + (c<<7) + (r<<3) + e
//       nblk=n>>4, c=d>>3, r=n&15, e=d&7
//   Vtf offset(shorts) = (b<<20) + (nblk<<10) + (d<<4) + (n&15)
// grid 1024 x 512 rows (4 waves x 16-row strips x 8 groups, prefetch 1 ahead)
// ---------------------------------------------------------------------------
__global__ void __launch_bounds__(256) proj_kernel(
    const float* __restrict__ x, const float* __restrict__ gin, const float* __restrict__ bin,
    const unsigned short* __restrict__ Wkb, const unsigned short* __restrict__ Wvb,
    unsigned short* __restrict__ Kf, unsigned short* __restrict__ Vtf)
{
  const int blk = blockIdx.x;
  const int tid = threadIdx.x, wave = tid >> 6, lane = tid & 63;
  const int l15 = lane & 15, quad = lane >> 4;
  const int b = blk >> 5;  // 32 blocks per batch
  const size_t row0 = ((size_t)blk << 9) + (wave << 4) + l15;
  const float* xp = x + row0 * 64 + quad * 8;

  const int k0 = quad * 8;
  f4 g0a = *(const f4*)(gin + k0),      g0b = *(const f4*)(gin + k0 + 4);
  f4 g1a = *(const f4*)(gin + k0 + 32), g1b = *(const f4*)(gin + k0 + 36);
  f4 h0a = *(const f4*)(bin + k0),      h0b = *(const f4*)(bin + k0 + 4);
  f4 h1a = *(const f4*)(bin + k0 + 32), h1b = *(const f4*)(bin + k0 + 36);

  f4 c0 = *(const f4*)xp, c1 = *(const f4*)(xp + 4);
  f4 c2 = *(const f4*)(xp + 32), c3 = *(const f4*)(xp + 36);

  for (int g = 0; g < 8; ++g) {
    f4 p0, p1, p2, p3;
    if (g < 7) {  // prefetch next group (64 rows ahead)
      const float* np = xp + (size_t)(g + 1) * 4096;
      p0 = *(const f4*)np;        p1 = *(const f4*)(np + 4);
      p2 = *(const f4*)(np + 32); p3 = *(const f4*)(np + 36);
    }
    float sm = 0.f, sq = 0.f;
#pragma unroll
    for (int j = 0; j < 4; ++j) {
      float v0 = c0[j], v1 = c1[j], v2 = c2[j], v3 = c3[j];
      sm += v0 + v1 + v2 + v3;
      sq += v0 * v0 + v1 * v1 + v2 * v2 + v3 * v3;
    }
    sm += __shfl_xor(sm, 16); sq += __shfl_xor(sq, 16);
    sm += __shfl_xor(sm, 32); sq += __shfl_xor(sq, 32);
    const float mean = sm * (1.f / 64.f);
    const float var = sq * (1.f / 64.f) - mean * mean;
    const float rstd = rsqrtf(var + 1e-5f);

    short8 a0, a1;
#pragma unroll
    for (int j = 0; j < 4; ++j) {
      a0[j]     = bfs((c0[j] - mean) * rstd * g0a[j] + h0a[j]);
      a0[j + 4] = bfs((c1[j] - mean) * rstd * g0b[j] + h0b[j]);
      a1[j]     = bfs((c2[j] - mean) * rstd * g1a[j] + h1a[j]);
      a1[j + 4] = bfs((c3[j] - mean) * rstd * g1b[j] + h1b[j]);
    }

    const int nblk = ((blk & 31) << 5) + (g << 2) + wave;  // 16-row strip in batch
    unsigned short* kbase = Kf + (((size_t)b << 20) + (nblk << 10));
    unsigned short* vbase = Vtf + (((size_t)b << 20) + (nblk << 10));

#pragma unroll
    for (int dt = 0; dt < 4; ++dt) {
      const unsigned short* wkp = Wkb + ((dt << 4) + l15) * 64 + k0;
      const unsigned short* wvp = Wvb + ((dt << 4) + l15) * 64 + k0;
      short8 wk0 = *(const short8*)wkp, wk1 = *(const short8*)(wkp + 32);
      short8 wv0 = *(const short8*)wvp, wv1 = *(const short8*)(wvp + 32);
      f4 ak = {0.f, 0.f, 0.f, 0.f}, av = {0.f, 0.f, 0.f, 0.f};
      ak = __builtin_amdgcn_mfma_f32_16x16x32_bf16(wk0, a0, ak, 0, 0, 0);
      ak = __builtin_amdgcn_mfma_f32_16x16x32_bf16(wk1, a1, ak, 0, 0, 0);
      av = __builtin_amdgcn_mfma_f32_16x16x32_bf16(a0, wv0, av, 0, 0, 0);
      av = __builtin_amdgcn_mfma_f32_16x16x32_bf16(a1, wv1, av, 0, 0, 0);
      // K: lane holds K[n=l15][d=dt*16+quad*4+reg] -> c=dt*2+(quad>>1), e=(quad&1)*4+reg
      uint2 kk;
      kk.x = f2bf(ak[0]) | (f2bf(ak[1]) << 16);
      kk.y = f2bf(ak[2]) | (f2bf(ak[3]) << 16);
      *(uint2*)(kbase + (((dt << 1) + (quad >> 1)) << 7) + (l15 << 3) + ((quad & 1) << 2)) = kk;
      // Vt: lane holds V[n=quad*4+reg][d=dt*16+l15]
      uint2 vv;
      vv.x = f2bf(av[0]) | (f2bf(av[1]) << 16);
      vv.y = f2bf(av[2]) | (f2bf(av[3]) << 16);
      *(uint2*)(vbase + (((dt << 4) + l15) << 4) + (quad << 2)) = vv;
    }
    c0 = p0; c1 = p1; c2 = p2; c3 = p3;
  }
}

// ---------------------------------------------------------------------------
// reduce (R4 compute, pipelined): grid 1024 = 32 b x 32 ch(512 rows), block
// 256 = 4 waves x 128 rows = 4 units of 32 rows. Unit u+1's 8 K/V loads are
// issued before unit u's softmax (software pipeline; regs rotate via unroll).
// ---------------------------------------------------------------------------
__global__ void __launch_bounds__(256) reduce_kernel(
    const unsigned short* __restrict__ Kf, const unsigned short* __restrict__ Vtf,
    const unsigned short* __restrict__ qb,
    float* __restrict__ Wpart, float* __restrict__ cpart)
{
  __shared__ __align__(16) unsigned short Pt[4][16][40];
  __shared__ float red[4][512];
  __shared__ float cred[4][8];

  const int tid = threadIdx.x, wave = tid >> 6, lane = tid & 63;
  const int l15 = lane & 15, quad = lane >> 4;
  const int b = blockIdx.x >> 5, ch = blockIdx.x & 31;

  const unsigned short* qrow = qb + (((b << 3) + (l15 & 7)) << 6) + quad * 8;
  short8 qf0 = *(const short8*)qrow;
  short8 qf1 = *(const short8*)(qrow + 32);

  const unsigned short* Kb = Kf + ((size_t)b << 20);
  const unsigned short* Vb = Vtf + ((size_t)b << 20);

  f4 wacc[4];
#pragma unroll
  for (int t = 0; t < 4; ++t) wacc[t] = (f4){0.f, 0.f, 0.f, 0.f};
  float cacc = 0.f;
  const int nblk_base = (ch << 5) + (wave << 3);  // 16-row tiles; unit u -> +2u

  short8 ck[4], cv[4];
  {
    const unsigned short* ka = Kb + (nblk_base << 10) + (quad << 7) + (l15 << 3);
    ck[0] = *(const short8*)ka;
    ck[1] = *(const short8*)(ka + 512);
    ck[2] = *(const short8*)(ka + 1024);
    ck[3] = *(const short8*)(ka + 1536);
#pragma unroll
    for (int t = 0; t < 4; ++t)
      cv[t] = *(const short8*)(Vb + ((size_t)(nblk_base + (quad >> 1)) << 10) +
                               (((t << 4) + l15) << 4) + ((quad & 1) << 3));
  }

#pragma unroll
  for (int u = 0; u < 4; ++u) {
    short8 nk[4], nv[4];
    if (u < 3) {  // prefetch unit u+1
      const int nblk = nblk_base + 2 * (u + 1);
      const unsigned short* ka = Kb + (nblk << 10) + (quad << 7) + (l15 << 3);
      nk[0] = *(const short8*)ka;
      nk[1] = *(const short8*)(ka + 512);
      nk[2] = *(const short8*)(ka + 1024);
      nk[3] = *(const short8*)(ka + 1536);
#pragma unroll
      for (int t = 0; t < 4; ++t)
        nv[t] = *(const short8*)(Vb + ((size_t)(nblk + (quad >> 1)) << 10) +
                                 (((t << 4) + l15) << 4) + ((quad & 1) << 3));
    }

#pragma unroll
    for (int h = 0; h < 2; ++h) {
      f4 lg = {0.f, 0.f, 0.f, 0.f};
      lg = __builtin_amdgcn_mfma_f32_16x16x32_bf16(ck[h * 2], qf0, lg, 0, 0, 0);
      lg = __builtin_amdgcn_mfma_f32_16x16x32_bf16(ck[h * 2 + 1], qf1, lg, 0, 0, 0);
      // lane: lg[n_local = quad*4+reg][s = l15&7 (dup at 8..15)]
      float p[4];
#pragma unroll
      for (int r2 = 0; r2 < 4; ++r2) {
        float e = __expf(lg[r2]);  // max-free: |logit| << 1
        float ss = e;
        ss += __shfl_xor(ss, 1);
        ss += __shfl_xor(ss, 2);
        ss += __shfl_xor(ss, 4);
        p[r2] = e * __builtin_amdgcn_rcpf(ss);
        cacc += p[r2];
      }
      unsigned short* pw = &Pt[wave][l15][h * 16 + quad * 4];
      *(unsigned int*)pw = f2bf(p[0]) | (f2bf(p[1]) << 16);
      *(unsigned int*)(pw + 2) = f2bf(p[2]) | (f2bf(p[3]) << 16);
    }
    // P^T in Pt[s][0..31]; A-frag (same-wave DS ordering, no barrier)
    short8 pf = *(const short8*)&Pt[wave][l15][quad * 8];
#pragma unroll
    for (int t = 0; t < 4; ++t)
      wacc[t] = __builtin_amdgcn_mfma_f32_16x16x32_bf16(pf, cv[t], wacc[t], 0, 0, 0);

#pragma unroll
    for (int i = 0; i < 4; ++i) { ck[i] = nk[i]; cv[i] = nv[i]; }
  }

  cacc += __shfl_xor(cacc, 16);
  cacc += __shfl_xor(cacc, 32);
  if (lane < 8) cred[wave][lane] = cacc;
  if (quad < 2) {  // C rows 8..15 are s-duplicates
#pragma unroll
    for (int t = 0; t < 4; ++t)
#pragma unroll
      for (int r2 = 0; r2 < 4; ++r2)
        red[wave][(quad * 4 + r2) * 64 + (t << 4) + l15] = wacc[t][r2];
  }
  __syncthreads();
  for (int i = tid; i < 512; i += 256)
    Wpart[(size_t)blockIdx.x * 512 + i] = red[0][i] + red[1][i] + red[2][i] + red[3][i];
  if (tid < 8)
    cpart[blockIdx.x * 8 + tid] = cred[0][tid] + cred[1][tid] + cred[2][tid] + cred[3][tid];
}

// ---------------------------------------------------------------------------
// update: per (b,s), 256 threads. 32 chunks now. GRU + LN + MLP + residual;
// emits next q when make_q.
// ---------------------------------------------------------------------------
__global__ void __launch_bounds__(256) update_kernel(
    const float* __restrict__ Wpart, const float* __restrict__ cpart,
    const float* __restrict__ slots, float* __restrict__ out,
    const float* __restrict__ W_ih, const float* __restrict__ W_hh,
    const float* __restrict__ b_ih, const float* __restrict__ b_hh,
    const float* __restrict__ g_mlp, const float* __restrict__ b_mlp,
    const float* __restrict__ W1, const float* __restrict__ b1,
    const float* __restrict__ W2, const float* __restrict__ b2,
    const float* __restrict__ gs, const float* __restrict__ bsl,
    const float* __restrict__ Wq, unsigned short* __restrict__ qb, int make_q)
{
  const int bs = blockIdx.x;
  const int b = bs >> 3, s = bs & 7;
  const int tid = threadIdx.x;
  const int l = tid & 63, cq = tid >> 6;
  __shared__ float wred[4][64];
  __shared__ float credS[4];
  __shared__ float u_sh[64], sp_sh[64], giA[192], ghA[192], uln_sh[64], h_sh[128];

  float wp = 0.f, cp2 = 0.f;
  for (int c = cq * 8; c < cq * 8 + 8; ++c) {
    wp += Wpart[(size_t)(((b << 5) + c) * 8 + s) * 64 + l];
    cp2 += cpart[((b << 5) + c) * 8 + s];
  }
  wred[cq][l] = wp;
  if (l == 0) credS[cq] = cp2;
  __syncthreads();

  float sp = 0.f;
  if (tid < 64) {
    const float cs = credS[0] + credS[1] + credS[2] + credS[3];
    const float u = (wred[0][l] + wred[1][l] + wred[2][l] + wred[3][l]) / cs;
    sp = slots[(b * 8 + s) * 64 + l];
    u_sh[l] = u; sp_sh[l] = sp;
  }
  __syncthreads();

  if (tid < 192) {
    float accI = b_ih[tid], accH = b_hh[tid];
    const float* wi = W_ih + tid * 64;
    const float* wh = W_hh + tid * 64;
    for (int k = 0; k < 64; ++k) { accI += u_sh[k] * wi[k]; accH += sp_sh[k] * wh[k]; }
    giA[tid] = accI; ghA[tid] = accH;
  }
  __syncthreads();

  float upd = 0.f;
  if (tid < 64) {
    const float rg = 1.f / (1.f + __expf(-(giA[l] + ghA[l])));
    const float zg = 1.f / (1.f + __expf(-(giA[64 + l] + ghA[64 + l])));
    const float ng = tanhf(giA[128 + l] + rg * ghA[128 + l]);
    upd = (1.f - zg) * ng + zg * sp;
    float sm = upd, sq = upd * upd;
#pragma unroll
    for (int m = 1; m < 64; m <<= 1) { sm += __shfl_xor(sm, m); sq += __shfl_xor(sq, m); }
    const float mean = sm * (1.f / 64.f);
    const float var = sq * (1.f / 64.f) - mean * mean;
    uln_sh[l] = (upd - mean) * rsqrtf(var + 1e-5f) * g_mlp[l] + b_mlp[l];
  }
  __syncthreads();

  if (tid < 128) {
    float acc = b1[tid];
    const float* w1 = W1 + tid * 64;
    for (int k = 0; k < 64; ++k) acc += uln_sh[k] * w1[k];
    h_sh[tid] = fmaxf(acc, 0.f);
  }
  __syncthreads();

  if (tid < 64) {
    float acc = b2[l];
    const float* w2 = W2 + l * 128;
    for (int k = 0; k < 128; ++k) acc += h_sh[k] * w2[k];
    const float sv = upd + acc;
    out[(b * 8 + s) * 64 + l] = sv;
    if (make_q) {
      float sm2 = sv, sq2 = sv * sv;
#pragma unroll
      for (int m = 1; m < 64; m <<= 1) { sm2 += __shfl_xor(sm2, m); sq2 += __shfl_xor(sq2, m); }
      const float mean2 = sm2 * (1.f / 64.f);
      const float var2 = sq2 * (1.f / 64.f) - mean2 * mean2;
      u_sh[l] = (sv - mean2) * rsqrtf(var2 + 1e-5f) * gs[l] + bsl[l];
      float qa = 0.f;
      const float* w = Wq + l * 64;
      for (int k = 0; k < 64; ++k) qa += u_sh[k] * w[k];
      qb[(b * 8 + s) * 64 + l] = (unsigned short)f2bf(qa * 0.125f);
    }
  }
}

// ---------------------------------------------------------------------------
extern "C" void kernel_launch(void* const* d_in, const int* in_sizes, int n_in,
                              void* d_out, int out_size, void* d_ws, size_t ws_size,
                              hipStream_t stream) {
  const float* x       = (const float*)d_in[0];
  const float* noise   = (const float*)d_in[1];
  const float* mu      = (const float*)d_in[2];
  const float* lsig    = (const float*)d_in[3];
  const float* ln_in_g = (const float*)d_in[4];
  const float* ln_in_b = (const float*)d_in[5];
  const float* ln_sl_g = (const float*)d_in[6];
  const float* ln_sl_b = (const float*)d_in[7];
  const float* ln_ml_g = (const float*)d_in[8];
  const float* ln_ml_b = (const float*)d_in[9];
  const float* Wq      = (const float*)d_in[10];
  const float* Wk      = (const float*)d_in[11];
  const float* Wv      = (const float*)d_in[12];
  const float* W_ih    = (const float*)d_in[13];
  const float* W_hh    = (const float*)d_in[14];
  const float* b_ih    = (const float*)d_in[15];
  const float* b_hh    = (const float*)d_in[16];
  const float* W1      = (const float*)d_in[17];
  const float* b1      = (const float*)d_in[18];
  const float* W2      = (const float*)d_in[19];
  const float* b2      = (const float*)d_in[20];

  unsigned short* Kw  = (unsigned short*)d_ws;
  unsigned short* Vt  = Kw + (size_t)BB * NN * 64;
  unsigned short* Wkb = Vt + (size_t)BB * NN * 64;
  unsigned short* Wvb = Wkb + 4096;
  unsigned short* qb  = Wvb + 4096;
  float* slots = (float*)(qb + 16384);
  float* Wpart = slots + 32 * 8 * 64;
  float* cpart = Wpart + (size_t)1024 * 512;

  prep_kernel<<<dim3(16), dim3(256), 0, stream>>>(Wk, Wv, Wkb, Wvb);
  init_q_kernel<<<dim3(256), dim3(64), 0, stream>>>(
      noise, mu, lsig, slots, ln_sl_g, ln_sl_b, Wq, qb);
  proj_kernel<<<dim3(1024), dim3(256), 0, stream>>>(
      x, ln_in_g, ln_in_b, Wkb, Wvb, Kw, Vt);

  for (int it = 0; it < 3; ++it) {
    reduce_kernel<<<dim3(1024), dim3(256), 0, stream>>>(Kw, Vt, qb, Wpart, cpart);
    update_kernel<<<dim3(256), dim3(256), 0, stream>>>(
        Wpart, cpart, slots, (it == 2) ? (float*)d_out : slots,
        W_ih, W_hh, b_ih, b_hh, ln_ml_g, ln_ml_b, W1, b1, W2, b2,
        ln_sl_g, ln_sl_b, Wq, qb, (it < 2) ? 1 : 0);
  }
}